// Round 15
// baseline (63.428 us; speedup 1.0000x reference)
//
#include <hip/hip_runtime.h>

// GraphAttention — round 15: dispatch-count cut, isolated this time.
// Ladder: best = r9/r10 structure @ 56.0. Nulls: r10/r14 B-path (vec+scalar), r4 bytes,
//   r3/r9 occupancy. Regressions: r11 barriers, r12 (cvt-fusion BUNDLED with bq[4][4]
//   register bloat -> cause ambiguous), r13 1-wave blocks.
// r15: prep fused into proj ONLY (inline v_cvt_pk_bf16_f32 on f32 x/W; adj mask at
//   blockIdx.z==3). attn + comb_ln BYTE-IDENTICAL to r10's 56.05 submission.
//   4 -> 3 dispatches; xb/wb staging round-trip deleted.
// lrelu(x,0.2)==0.6x+0.4|x| -> s = 0.6(sa_i+sb_j)+0.4*sum af*|A+B| (exp2 domain);
// no softmax max (s is O(1), validated r5+); mask via bit-select.

#define NB 2
#define NN 512
#define DM 512
#define NH 16
#define DD 32
#define RLOG2E 1.4426950408889634f

typedef __attribute__((ext_vector_type(8))) short bf16x8;
typedef __attribute__((ext_vector_type(4))) float f32x4;
typedef _Float16 h2 __attribute__((ext_vector_type(2)));
typedef _Float16 h8 __attribute__((ext_vector_type(8)));
typedef __fp16 fp16x2 __attribute__((ext_vector_type(2)));

__device__ __forceinline__ h2 u2h(unsigned int u) { union { unsigned int x; h2 h; } c; c.x = u; return c.h; }
__device__ __forceinline__ unsigned int h2u(h2 v) { union { unsigned int x; h2 h; } c; c.h = v; return c.x; }
__device__ __forceinline__ h8 u4h8(uint4 v) { union { uint4 u; h8 h; } c; c.u = v; return c.h; }
__device__ __forceinline__ h2 pkrtz(float x, float y) {
  union { fp16x2 a; h2 b; } c; c.a = __builtin_amdgcn_cvt_pkrtz(x, y); return c.b;
}
// f32x8 -> packed bf16x8 (RNE) via gfx950 v_cvt_pk_bf16_f32 (no builtin)
__device__ __forceinline__ bf16x8 pk_bf8(float4 lo, float4 hi) {
  union { unsigned int u[4]; bf16x8 v; } c;
  asm("v_cvt_pk_bf16_f32 %0, %1, %2" : "=v"(c.u[0]) : "v"(lo.x), "v"(lo.y));
  asm("v_cvt_pk_bf16_f32 %0, %1, %2" : "=v"(c.u[1]) : "v"(lo.z), "v"(lo.w));
  asm("v_cvt_pk_bf16_f32 %0, %1, %2" : "=v"(c.u[2]) : "v"(hi.x), "v"(hi.y));
  asm("v_cvt_pk_bf16_f32 %0, %1, %2" : "=v"(c.u[3]) : "v"(hi.z), "v"(hi.w));
  return c.v;
}

#if __has_builtin(__builtin_amdgcn_fdot2)
#define DOT2(a, b, c) __builtin_amdgcn_fdot2((a), (b), (c), false)
#else
#define DOT2(a, b, c) fmaf((float)(a)[0], (float)(b)[0], fmaf((float)(a)[1], (float)(b)[1], (c)))
#endif

// ---------------- kernel 1: proj (f32 in, inline bf16 cvt) + fused sa/sb + mask ----
// grid (16, 8, 4), block 256: z<3 -> P = x @ W^T + b (bf16 MFMA, f16 out);
// z==3 -> adj bitmask (independent work, no ordering hazard).
__global__ void proj_kernel(const float* __restrict__ x,
                            const float* __restrict__ w0, const float* __restrict__ w1,
                            const float* __restrict__ w2, const float* __restrict__ adj,
                            const float* __restrict__ bias0, const float* __restrict__ bias1,
                            const float* __restrict__ bias2,
                            const float* __restrict__ aff,
                            _Float16* __restrict__ Pfch, _Float16* __restrict__ Pfc2h,
                            _Float16* __restrict__ Pvalh,
                            float* __restrict__ sa, float* __restrict__ sb,
                            unsigned int* __restrict__ bits) {
  const int which = blockIdx.z;
  const int tid = threadIdx.x;
  if (which == 3) {
    int t = (blockIdx.x * 8 + blockIdx.y) * 256 + tid;   // 0..32767
    if (t < 16384) {
      int bb = t >> 13, rem = t & 8191;
      int i = rem >> 4, jw = rem & 15;
      const float4* ap = (const float4*)(adj + ((size_t)(bb * NN + i)) * NN + jw * 32);
      unsigned int word = 0;
      #pragma unroll
      for (int q = 0; q < 8; ++q) {
        float4 v = ap[q];
        if (v.x >= 1e-5f) word |= 1u << (q * 4 + 0);
        if (v.y >= 1e-5f) word |= 1u << (q * 4 + 1);
        if (v.z >= 1e-5f) word |= 1u << (q * 4 + 2);
        if (v.w >= 1e-5f) word |= 1u << (q * 4 + 3);
      }
      bits[((bb * 16) + jw) * 512 + i] = word;
    }
    return;
  }
  const float* W     = (which == 0) ? w0 : (which == 1) ? w1 : w2;
  const float* bias  = (which == 0) ? bias0 : (which == 1) ? bias1 : bias2;
  _Float16* Ph       = (which == 0) ? Pfch : (which == 1) ? Pfc2h : Pvalh;
  const int mt = blockIdx.x, nt = blockIdx.y;
  const int wv = tid >> 6, lane = tid & 63;
  const int wm = wv >> 1, wn = wv & 1;
  const int mbase = mt * 64 + wm * 32, nbase = nt * 64 + wn * 32;
  const int lr = lane & 15, lk = lane >> 4;
  const float4* A0f = (const float4*)(x + (size_t)(mbase + lr) * 512 + lk * 8);
  const float4* A1f = (const float4*)(x + (size_t)(mbase + 16 + lr) * 512 + lk * 8);
  const float4* B0f = (const float4*)(W + (size_t)(nbase + lr) * 512 + lk * 8);
  const float4* B1f = (const float4*)(W + (size_t)(nbase + 16 + lr) * 512 + lk * 8);
  f32x4 acc00 = {0.f, 0.f, 0.f, 0.f}, acc01 = acc00, acc10 = acc00, acc11 = acc00;
  #pragma unroll
  for (int kt = 0; kt < 16; ++kt) {
    bf16x8 a0 = pk_bf8(A0f[kt * 8], A0f[kt * 8 + 1]);
    bf16x8 a1 = pk_bf8(A1f[kt * 8], A1f[kt * 8 + 1]);
    bf16x8 b0 = pk_bf8(B0f[kt * 8], B0f[kt * 8 + 1]);
    bf16x8 b1 = pk_bf8(B1f[kt * 8], B1f[kt * 8 + 1]);
    acc00 = __builtin_amdgcn_mfma_f32_16x16x32_bf16(a0, b0, acc00, 0, 0, 0);
    acc01 = __builtin_amdgcn_mfma_f32_16x16x32_bf16(a0, b1, acc01, 0, 0, 0);
    acc10 = __builtin_amdgcn_mfma_f32_16x16x32_bf16(a1, b0, acc10, 0, 0, 0);
    acc11 = __builtin_amdgcn_mfma_f32_16x16x32_bf16(a1, b1, acc11, 0, 0, 0);
  }
  // C/D: col = lane&15, row = (lane>>4)*4 + v
  const int r0 = mbase + lk * 4, cb = nbase + lr;
  const int hw = nt * 2 + wn;                 // head this wave covers
  const float afA = aff[hw * 32 + lr];
  const float afB = aff[hw * 32 + lr + 16];
  float pa[4], pb[4];
  #pragma unroll
  for (int v = 0; v < 4; ++v) {
    float r00 = acc00[v] + bias[cb];
    float r01 = acc01[v] + bias[cb + 16];
    float r10 = acc10[v] + bias[cb];
    float r11 = acc11[v] + bias[cb + 16];
    Ph[(size_t)(r0 + v) * 512 + cb]           = (_Float16)r00;
    Ph[(size_t)(r0 + v) * 512 + cb + 16]      = (_Float16)r01;
    Ph[(size_t)(r0 + 16 + v) * 512 + cb]      = (_Float16)r10;
    Ph[(size_t)(r0 + 16 + v) * 512 + cb + 16] = (_Float16)r11;
    pa[v] = fmaf(afA, r00, afB * r01);
    pb[v] = fmaf(afA, r10, afB * r11);
  }
  if (which < 2) {
    #pragma unroll
    for (int m = 1; m < 16; m <<= 1) {
      #pragma unroll
      for (int v = 0; v < 4; ++v) {
        pa[v] += __shfl_xor(pa[v], m);
        pb[v] += __shfl_xor(pb[v], m);
      }
    }
    if (lr == 0) {
      float* dst = (which == 0) ? sa : sb;
      const float sc = 0.6f * RLOG2E;
      #pragma unroll
      for (int v = 0; v < 4; ++v) {
        int g0 = r0 + v, g1 = r0 + 16 + v;    // global rows (b*512+i)
        dst[((g0 >> 9) * NH + hw) * NN + (g0 & 511)] = pa[v] * sc;
        dst[((g1 >> 9) * NH + hw) * NN + (g1 & 511)] = pb[v] * sc;
      }
    }
  }
}

// ---------------- kernel 2: attention — r10 verbatim (measured 56.05 base) ----------
// grid (64 = 8 it(64 rows) x 8 jh(64 j), 16 h, 2 b) = 2048 blocks, block 256 = 4 waves.
// Wave w: j in [w*16, w*16+16); lane owns row i = it*64+lane.
// B rows via uniform-address vector loads (proven perf-equivalent to s_load, r14).
// P tile LDS [64r][64j] f16 (chunk ^ (r&7)); PV via mfma 16x16x32 f16.
__launch_bounds__(256)
__global__ void attn_kernel(const _Float16* __restrict__ Pfch,
                            const _Float16* __restrict__ Pfc2h,
                            const _Float16* __restrict__ Pvalh,
                            const float* __restrict__ sa, const float* __restrict__ sb,
                            const float* __restrict__ aff,
                            const unsigned int* __restrict__ bits,
                            float* __restrict__ part_l, _Float16* __restrict__ part_oh) {
  const int bx = blockIdx.x;
  const int it = bx >> 3, jh = bx & 7;
  const int h = blockIdx.y, b = blockIdx.z;
  const int tid = threadIdx.x;
  const int w = tid >> 6, lane = tid & 63;
  const int wu = __builtin_amdgcn_readfirstlane(w);   // SGPR-uniform wave id
  const int i = it * 64 + lane;
  const int jbase = jh * 64;

  __shared__ uint4 VtT4[256];       // [d(32)][j(64)] f16 transposed, chunk ^ (d&7)
  __shared__ uint4 Pt4[512];        // [r(64)][j(64)] f16, chunk ^ (r&7)
  __shared__ float slm[4][64];
  __shared__ float sbt[64];

  // ---- stage V^T (swizzled transpose) + sbt ----
  {
    const int row = tid >> 2, seg = tid & 3;
    uint4 vv = *(const uint4*)(Pvalh + ((size_t)(b * NN + jbase + row)) * DM + h * DD + seg * 8);
    _Float16* VtT_h = (_Float16*)VtT4;
    const int jc = row >> 3, jr = row & 7;    // j-chunk, j-within
    #pragma unroll
    for (int e = 0; e < 4; ++e) {
      h2 pr = u2h(((const unsigned int*)&vv)[e]);
      int d0 = seg * 8 + 2 * e, d1 = d0 + 1;
      VtT_h[d0 * 64 + ((jc ^ (d0 & 7)) * 8) + jr] = pr[0];
      VtT_h[d1 * 64 + ((jc ^ (d1 & 7)) * 8) + jr] = pr[1];
    }
    if (tid < 64) sbt[tid] = sb[(b * NH + h) * NN + jbase + tid];
  }

  // ---- per-lane packed A / aff state ----
  h2 ah[16], afh[16];
  {
    const uint4* ap = (const uint4*)(Pfch + ((size_t)(b * NN + i)) * DM + h * DD);
    #pragma unroll
    for (int q = 0; q < 4; ++q) {
      uint4 v0 = ap[q];
      ah[q * 4 + 0] = u2h(v0.x); ah[q * 4 + 1] = u2h(v0.y);
      ah[q * 4 + 2] = u2h(v0.z); ah[q * 4 + 3] = u2h(v0.w);
    }
    const float4* fp = (const float4*)(aff + h * DD);
    const float afs = 0.4f * RLOG2E;
    #pragma unroll
    for (int q = 0; q < 8; ++q) {
      float4 fv = fp[q];
      afh[q * 2 + 0] = pkrtz(fv.x * afs, fv.y * afs);
      afh[q * 2 + 1] = pkrtz(fv.z * afs, fv.w * afs);
    }
  }
  const float sai = sa[(b * NH + h) * NN + i];
  const unsigned int mw = bits[((b * 16) + jh * 2 + (wu >> 1)) * NN + i] >> ((wu & 1) * 16);
  float l = 0.f;
  h2 ph[8];   // packed p for this wave's 16 j

  // wave-uniform base of this wave's B rows
  const uint4* Bw = (const uint4*)(Pfc2h + ((size_t)(b * NN + jbase + wu * 16)) * DM + h * DD);

  __syncthreads();

  // ---- phase 1: branch-free score loop (2 j per iter for static pkrtz packing) ----
  #pragma unroll
  for (int jp = 0; jp < 8; ++jp) {
    float pv2[2];
    #pragma unroll
    for (int q = 0; q < 2; ++q) {
      const int jo = jp * 2 + q;
      const uint4* bp = Bw + (size_t)jo * (DM / 8);
      uint4 bq0 = bp[0], bq1 = bp[1], bq2 = bp[2], bq3 = bp[3];
      float t0 = 0.f, t1 = 0.f;
      #define SC2(k, dw, T)                                          \
        { h2 bh = u2h(dw);                                           \
          h2 u0 = u2h(h2u(ah[k] + bh) & 0x7FFF7FFFu);                \
          T = DOT2(afh[k], u0, T); }
      SC2(0,  bq0.x, t0) SC2(1,  bq0.y, t1)
      SC2(2,  bq0.z, t0) SC2(3,  bq0.w, t1)
      SC2(4,  bq1.x, t0) SC2(5,  bq1.y, t1)
      SC2(6,  bq1.z, t0) SC2(7,  bq1.w, t1)
      SC2(8,  bq2.x, t0) SC2(9,  bq2.y, t1)
      SC2(10, bq2.z, t0) SC2(11, bq2.w, t1)
      SC2(12, bq3.x, t0) SC2(13, bq3.y, t1)
      SC2(14, bq3.z, t0) SC2(15, bq3.w, t1)
      #undef SC2
      const float s = sai + sbt[wu * 16 + jo] + (t0 + t1);
      const float p = ((mw >> jo) & 1u) ? __builtin_amdgcn_exp2f(s) : 0.f;
      l += p;
      pv2[q] = p;
    }
    ph[jp] = pkrtz(pv2[0], pv2[1]);
  }

  slm[wu][lane] = l;
  // write P row chunks (16 j = 2 x 16B), XOR swizzle chunk ^ (row&7)
  {
    const int c0 = 2 * wu, c1 = 2 * wu + 1;
    uint4 q0 = make_uint4(h2u(ph[0]), h2u(ph[1]), h2u(ph[2]), h2u(ph[3]));
    uint4 q1 = make_uint4(h2u(ph[4]), h2u(ph[5]), h2u(ph[6]), h2u(ph[7]));
    Pt4[lane * 8 + (c0 ^ (lane & 7))] = q0;
    Pt4[lane * 8 + (c1 ^ (lane & 7))] = q1;
  }
  __syncthreads();

  // ---- phase 2: O = P·V via MFMA 16x16x32 f16; wave w -> row-tile w ----
  {
    const int lr = lane & 15, lk = lane >> 4;
    const int row = wu * 16 + lr;
    uint4 a4_0 = Pt4[row * 8 + ((lk) ^ (row & 7))];
    uint4 a4_1 = Pt4[row * 8 + ((4 + lk) ^ (row & 7))];
    #pragma unroll
    for (int ct = 0; ct < 2; ++ct) {
      const int d = ct * 16 + lr;
      uint4 b4_0 = VtT4[d * 8 + ((lk) ^ (d & 7))];
      uint4 b4_1 = VtT4[d * 8 + ((4 + lk) ^ (d & 7))];
      f32x4 acc = {0.f, 0.f, 0.f, 0.f};
      acc = __builtin_amdgcn_mfma_f32_16x16x32_f16(u4h8(a4_0), u4h8(b4_0), acc, 0, 0, 0);
      acc = __builtin_amdgcn_mfma_f32_16x16x32_f16(u4h8(a4_1), u4h8(b4_1), acc, 0, 0, 0);
      // D: col = lane&15, row = (lane>>4)*4 + v
      #pragma unroll
      for (int v = 0; v < 4; ++v) {
        const int grow = it * 64 + wu * 16 + lk * 4 + v;
        const size_t prow = (((size_t)(jh * 2 + b) * NH + h) * NN + grow);
        part_oh[prow * 32 + ct * 16 + lr] = (_Float16)acc[v];
      }
    }
    if (tid < 64) {
      const size_t prow = (((size_t)(jh * 2 + b) * NH + h) * NN + it * 64 + tid);
      part_l[prow] = (slm[0][tid] + slm[1][tid]) + (slm[2][tid] + slm[3][tid]);
    }
  }
}

// ---------------- kernel 3: combine(8 slots) + residual + layernorm + relu ----------------
// grid 128 blocks x 256 thr; block = 8 rows; 32 threads/row, 16 d's each.
__global__ void comb_ln_kernel(const unsigned int* __restrict__ part_o,
                               const float* __restrict__ part_l,
                               const _Float16* __restrict__ Pfch,
                               const float* __restrict__ g, const float* __restrict__ be,
                               float* __restrict__ out) {
  const int t = threadIdx.x;
  const int rg = blockIdx.x * 8 + (t >> 5);     // global row 0..1023
  const int b = rg >> 9, i = rg & 511;
  const int l32 = t & 31;
  const int d0 = l32 * 16;
  const int h0 = d0 >> 5;
  const int dh = d0 & 31;                        // 0 or 16
  float o[16];
  #pragma unroll
  for (int k = 0; k < 16; ++k) o[k] = 0.f;
  float L = 0.f;
  #pragma unroll
  for (int s = 0; s < 8; ++s) {
    const size_t prow = (((size_t)(s * 2 + b) * NH + h0) * NN + i);
    L += part_l[prow];
    const uint4* po = (const uint4*)(part_o + prow * 16 + (dh >> 1));
    uint4 q0 = po[0], q1 = po[1];
    #define ACC(k, dw) { h2 hh = u2h(dw); o[2*(k)] += (float)hh[0]; o[2*(k)+1] += (float)hh[1]; }
    ACC(0, q0.x) ACC(1, q0.y) ACC(2, q0.z) ACC(3, q0.w)
    ACC(4, q1.x) ACC(5, q1.y) ACC(6, q1.z) ACC(7, q1.w)
    #undef ACC
  }
  const float inv = 1.f / L;
  // residual x_aff_flat from f16 Pfch
  const uint4* pfh = (const uint4*)(Pfch + ((size_t)(b * NN + i)) * DM + d0);
  uint4 r0 = pfh[0], r1 = pfh[1];
  float pfv[16];
  #define UNP(k, dw) { h2 hh = u2h(dw); pfv[2*(k)] = (float)hh[0]; pfv[2*(k)+1] = (float)hh[1]; }
  UNP(0, r0.x) UNP(1, r0.y) UNP(2, r0.z) UNP(3, r0.w)
  UNP(4, r1.x) UNP(5, r1.y) UNP(6, r1.z) UNP(7, r1.w)
  #undef UNP
  float hv[16];
  float sS = 0.f, sQ = 0.f;
  #pragma unroll
  for (int k = 0; k < 16; ++k) {
    float hvv = pfv[k] + o[k] * inv;
    hv[k] = hvv;
    sS += hvv;
    sQ = fmaf(hvv, hvv, sQ);
  }
  #pragma unroll
  for (int off = 16; off > 0; off >>= 1) {
    sS += __shfl_xor(sS, off);
    sQ += __shfl_xor(sQ, off);
  }
  const float mu = sS * (1.f / 512.f);
  const float var = sQ * (1.f / 512.f) - mu * mu;
  const float rstd = rsqrtf(var + 1e-5f);
  float4* op = (float4*)(out + ((size_t)(b * NN + i)) * DM + d0);
  #pragma unroll
  for (int k = 0; k < 4; ++k) {
    float4 gv = ((const float4*)(g + d0))[k];
    float4 bv = ((const float4*)(be + d0))[k];
    float4 res;
    res.x = fmaxf((hv[4 * k + 0] - mu) * rstd * gv.x + bv.x, 0.f);
    res.y = fmaxf((hv[4 * k + 1] - mu) * rstd * gv.y + bv.y, 0.f);
    res.z = fmaxf((hv[4 * k + 2] - mu) * rstd * gv.z + bv.z, 0.f);
    res.w = fmaxf((hv[4 * k + 3] - mu) * rstd * gv.w + bv.w, 0.f);
    op[k] = res;
  }
}

extern "C" void kernel_launch(void* const* d_in, const int* in_sizes, int n_in,
                              void* d_out, int out_size, void* d_ws, size_t ws_size,
                              hipStream_t stream) {
  const float* x    = (const float*)d_in[0];
  const float* adj  = (const float*)d_in[1];
  const float* Wfc  = (const float*)d_in[2];
  const float* bfc  = (const float*)d_in[3];
  const float* Wfc2 = (const float*)d_in[4];
  const float* bfc2 = (const float*)d_in[5];
  const float* Wval = (const float*)d_in[6];
  const float* bval = (const float*)d_in[7];
  const float* aff  = (const float*)d_in[8];
  // d_in[9] = aff_bias: softmax-invariant, skipped
  const float* lng  = (const float*)d_in[10];
  const float* lnb  = (const float*)d_in[11];
  float* out = (float*)d_out;

  char* ws = (char*)d_ws;
  _Float16* part_oh = (_Float16*)(ws);                  // 8.4 MB
  float* part_l   = (float*)(ws + 8388608);             // 512 KB
  _Float16* Pfch  = (_Float16*)(ws + 8912896);          // 1 MB
  _Float16* Pfc2h = (_Float16*)(ws + 9961472);          // 1 MB
  _Float16* Pvalh = (_Float16*)(ws + 11010048);         // 1 MB
  float* sa       = (float*)(ws + 12058624);            // 64 KB
  float* sb       = (float*)(ws + 12124160);            // 64 KB
  unsigned int* bits = (unsigned int*)(ws + 12189696);  // 64 KB
  // footprint: 12,255,232 bytes

  proj_kernel<<<dim3(16, 8, 4), 256, 0, stream>>>(x, Wfc, Wfc2, Wval, adj, bfc, bfc2, bval,
                                                  aff, Pfch, Pfc2h, Pvalh, sa, sb, bits);
  attn_kernel<<<dim3(64, 16, 2), 256, 0, stream>>>(Pfch, Pfc2h, Pvalh, sa, sb, aff, bits,
                                                   part_l, part_oh);
  comb_ln_kernel<<<128, 256, 0, stream>>>((const unsigned int*)part_oh, part_l, Pfch,
                                          lng, lnb, out);
}

// Round 16
// 55.849 us; speedup vs baseline: 1.1357x; 1.1357x over previous
//
#include <hip/hip_runtime.h>

// GraphAttention — round 16: REVERT to measured optimum (r10 submission, 56.05 us).
// Final ledger (7 structural departures, all worse or null):
//   occupancy x2/x4 (r3,r9,r13): +-3us | bytes /4 (r4): null | B-path vec->scalar
//   (r10,r14): null | barriers -2 (r11): +7us | score ILP batch (r12): regress |
//   cvt-fusion (r12,r15): regress (+2x proj bytes, broken MFMA pipelining).
// Positives all came from critical-path instruction cuts: r5 LDS+branchfree (75->52),
//   r7 packed-f16 (attn ~40), r8 MFMA-PV (59.3), r9 1-row/lane + fused aux (56.0).
// lrelu(x,0.2)==0.6x+0.4|x| -> s = 0.6(sa_i+sb_j)+0.4*sum af*|A+B| (exp2 domain);
// no softmax max (s is O(1), validated r5+); mask via bit-select.

#define NB 2
#define NN 512
#define DM 512
#define NH 16
#define DD 32
#define RLOG2E 1.4426950408889634f

typedef __attribute__((ext_vector_type(8))) short bf16x8;
typedef __attribute__((ext_vector_type(4))) float f32x4;
typedef _Float16 h2 __attribute__((ext_vector_type(2)));
typedef _Float16 h8 __attribute__((ext_vector_type(8)));
typedef __fp16 fp16x2 __attribute__((ext_vector_type(2)));

__device__ __forceinline__ h2 u2h(unsigned int u) { union { unsigned int x; h2 h; } c; c.x = u; return c.h; }
__device__ __forceinline__ unsigned int h2u(h2 v) { union { unsigned int x; h2 h; } c; c.h = v; return c.x; }
__device__ __forceinline__ h8 u4h8(uint4 v) { union { uint4 u; h8 h; } c; c.u = v; return c.h; }
__device__ __forceinline__ h2 pkrtz(float x, float y) {
  union { fp16x2 a; h2 b; } c; c.a = __builtin_amdgcn_cvt_pkrtz(x, y); return c.b;
}

#if __has_builtin(__builtin_amdgcn_fdot2)
#define DOT2(a, b, c) __builtin_amdgcn_fdot2((a), (b), (c), false)
#else
#define DOT2(a, b, c) fmaf((float)(a)[0], (float)(b)[0], fmaf((float)(a)[1], (float)(b)[1], (c)))
#endif

__device__ __forceinline__ unsigned short f2bf(float f) {
  unsigned int u = __float_as_uint(f);
  u = (u + 0x7FFFu + ((u >> 16) & 1u)) >> 16;   // RNE
  return (unsigned short)u;
}

// ---------------- kernel 1: conv(x,W->bf16) + adj->bitmask, fused ----------------
__global__ void prep_kernel(const float* __restrict__ x, const float* __restrict__ w0,
                            const float* __restrict__ w1, const float* __restrict__ w2,
                            const float* __restrict__ adj,
                            unsigned short* __restrict__ xb, unsigned short* __restrict__ wb0,
                            unsigned short* __restrict__ wb1, unsigned short* __restrict__ wb2,
                            unsigned int* __restrict__ bits) {
  int gid = blockIdx.x * 256 + threadIdx.x;
  if (gid < 327680) {
    const float* src; unsigned short* dst; int off;
    if (gid < 131072)      { src = x;  dst = xb;  off = gid; }
    else if (gid < 196608) { src = w0; dst = wb0; off = gid - 131072; }
    else if (gid < 262144) { src = w1; dst = wb1; off = gid - 196608; }
    else                   { src = w2; dst = wb2; off = gid - 262144; }
    float4 v = ((const float4*)src)[off];
    ushort4 r;
    r.x = f2bf(v.x); r.y = f2bf(v.y); r.z = f2bf(v.z); r.w = f2bf(v.w);
    ((ushort4*)dst)[off] = r;
  } else {
    int t = gid - 327680;                 // 16384 mask words
    if (t < 16384) {
      int bb = t >> 13, rem = t & 8191;
      int i = rem >> 4, jw = rem & 15;
      const float4* ap = (const float4*)(adj + ((size_t)(bb * NN + i)) * NN + jw * 32);
      unsigned int word = 0;
      #pragma unroll
      for (int q = 0; q < 8; ++q) {
        float4 v = ap[q];
        if (v.x >= 1e-5f) word |= 1u << (q * 4 + 0);
        if (v.y >= 1e-5f) word |= 1u << (q * 4 + 1);
        if (v.z >= 1e-5f) word |= 1u << (q * 4 + 2);
        if (v.w >= 1e-5f) word |= 1u << (q * 4 + 3);
      }
      bits[((bb * 16) + jw) * 512 + i] = word;
    }
  }
}

// ---------------- kernel 2: P = x @ W^T + b (bf16 MFMA; f16 out) + fused sa/sb ------
__global__ void proj_kernel(const unsigned short* __restrict__ xb,
                            const unsigned short* __restrict__ wb0,
                            const unsigned short* __restrict__ wb1,
                            const unsigned short* __restrict__ wb2,
                            const float* __restrict__ bias0, const float* __restrict__ bias1,
                            const float* __restrict__ bias2,
                            const float* __restrict__ aff,
                            _Float16* __restrict__ Pfch, _Float16* __restrict__ Pfc2h,
                            _Float16* __restrict__ Pvalh,
                            float* __restrict__ sa, float* __restrict__ sb) {
  const int mt = blockIdx.x, nt = blockIdx.y, which = blockIdx.z;
  const unsigned short* W = (which == 0) ? wb0 : (which == 1) ? wb1 : wb2;
  const float* bias       = (which == 0) ? bias0 : (which == 1) ? bias1 : bias2;
  _Float16* Ph            = (which == 0) ? Pfch : (which == 1) ? Pfc2h : Pvalh;
  const int tid = threadIdx.x;
  const int wv = tid >> 6, lane = tid & 63;
  const int wm = wv >> 1, wn = wv & 1;
  const int mbase = mt * 64 + wm * 32, nbase = nt * 64 + wn * 32;
  const int lr = lane & 15, lk = lane >> 4;
  const bf16x8* A0 = (const bf16x8*)(xb + (size_t)(mbase + lr) * 512 + lk * 8);
  const bf16x8* A1 = (const bf16x8*)(xb + (size_t)(mbase + 16 + lr) * 512 + lk * 8);
  const bf16x8* B0 = (const bf16x8*)(W + (size_t)(nbase + lr) * 512 + lk * 8);
  const bf16x8* B1 = (const bf16x8*)(W + (size_t)(nbase + 16 + lr) * 512 + lk * 8);
  f32x4 acc00 = {0.f, 0.f, 0.f, 0.f}, acc01 = acc00, acc10 = acc00, acc11 = acc00;
  #pragma unroll
  for (int kt = 0; kt < 16; ++kt) {
    bf16x8 a0 = A0[kt * 4], a1 = A1[kt * 4];
    bf16x8 b0 = B0[kt * 4], b1 = B1[kt * 4];
    acc00 = __builtin_amdgcn_mfma_f32_16x16x32_bf16(a0, b0, acc00, 0, 0, 0);
    acc01 = __builtin_amdgcn_mfma_f32_16x16x32_bf16(a0, b1, acc01, 0, 0, 0);
    acc10 = __builtin_amdgcn_mfma_f32_16x16x32_bf16(a1, b0, acc10, 0, 0, 0);
    acc11 = __builtin_amdgcn_mfma_f32_16x16x32_bf16(a1, b1, acc11, 0, 0, 0);
  }
  // C/D: col = lane&15, row = (lane>>4)*4 + v
  const int r0 = mbase + lk * 4, cb = nbase + lr;
  const int hw = nt * 2 + wn;                 // head this wave covers
  const float afA = aff[hw * 32 + lr];
  const float afB = aff[hw * 32 + lr + 16];
  float pa[4], pb[4];
  #pragma unroll
  for (int v = 0; v < 4; ++v) {
    float r00 = acc00[v] + bias[cb];
    float r01 = acc01[v] + bias[cb + 16];
    float r10 = acc10[v] + bias[cb];
    float r11 = acc11[v] + bias[cb + 16];
    Ph[(size_t)(r0 + v) * 512 + cb]           = (_Float16)r00;
    Ph[(size_t)(r0 + v) * 512 + cb + 16]      = (_Float16)r01;
    Ph[(size_t)(r0 + 16 + v) * 512 + cb]      = (_Float16)r10;
    Ph[(size_t)(r0 + 16 + v) * 512 + cb + 16] = (_Float16)r11;
    pa[v] = fmaf(afA, r00, afB * r01);
    pb[v] = fmaf(afA, r10, afB * r11);
  }
  if (which < 2) {
    #pragma unroll
    for (int m = 1; m < 16; m <<= 1) {
      #pragma unroll
      for (int v = 0; v < 4; ++v) {
        pa[v] += __shfl_xor(pa[v], m);
        pb[v] += __shfl_xor(pb[v], m);
      }
    }
    if (lr == 0) {
      float* dst = (which == 0) ? sa : sb;
      const float sc = 0.6f * RLOG2E;
      #pragma unroll
      for (int v = 0; v < 4; ++v) {
        int g0 = r0 + v, g1 = r0 + 16 + v;    // global rows (b*512+i)
        dst[((g0 >> 9) * NH + hw) * NN + (g0 & 511)] = pa[v] * sc;
        dst[((g1 >> 9) * NH + hw) * NN + (g1 & 511)] = pb[v] * sc;
      }
    }
  }
}

// ---------------- kernel 3: attention — VALU scores + MFMA PV, 1 row/lane ----------
// grid (64 = 8 it(64 rows) x 8 jh(64 j), 16 h, 2 b) = 2048 blocks, block 256 = 4 waves.
// Wave w: j in [w*16, w*16+16); lane owns row i = it*64+lane.
// P tile LDS [64r][64j] f16 (chunk ^ (r&7)); PV via mfma 16x16x32 f16.
__launch_bounds__(256)
__global__ void attn_kernel(const _Float16* __restrict__ Pfch,
                            const _Float16* __restrict__ Pfc2h,
                            const _Float16* __restrict__ Pvalh,
                            const float* __restrict__ sa, const float* __restrict__ sb,
                            const float* __restrict__ aff,
                            const unsigned int* __restrict__ bits,
                            float* __restrict__ part_l, _Float16* __restrict__ part_oh) {
  const int bx = blockIdx.x;
  const int it = bx >> 3, jh = bx & 7;
  const int h = blockIdx.y, b = blockIdx.z;
  const int tid = threadIdx.x;
  const int w = tid >> 6, lane = tid & 63;
  const int wu = __builtin_amdgcn_readfirstlane(w);   // SGPR-uniform wave id
  const int i = it * 64 + lane;
  const int jbase = jh * 64;

  __shared__ uint4 VtT4[256];       // [d(32)][j(64)] f16 transposed, chunk ^ (d&7)
  __shared__ uint4 Pt4[512];        // [r(64)][j(64)] f16, chunk ^ (r&7)
  __shared__ float slm[4][64];
  __shared__ float sbt[64];

  // ---- stage V^T (swizzled transpose) + sbt ----
  {
    const int row = tid >> 2, seg = tid & 3;
    uint4 vv = *(const uint4*)(Pvalh + ((size_t)(b * NN + jbase + row)) * DM + h * DD + seg * 8);
    _Float16* VtT_h = (_Float16*)VtT4;
    const int jc = row >> 3, jr = row & 7;    // j-chunk, j-within
    #pragma unroll
    for (int e = 0; e < 4; ++e) {
      h2 pr = u2h(((const unsigned int*)&vv)[e]);
      int d0 = seg * 8 + 2 * e, d1 = d0 + 1;
      VtT_h[d0 * 64 + ((jc ^ (d0 & 7)) * 8) + jr] = pr[0];
      VtT_h[d1 * 64 + ((jc ^ (d1 & 7)) * 8) + jr] = pr[1];
    }
    if (tid < 64) sbt[tid] = sb[(b * NH + h) * NN + jbase + tid];
  }

  // ---- per-lane packed A / aff state ----
  h2 ah[16], afh[16];
  {
    const uint4* ap = (const uint4*)(Pfch + ((size_t)(b * NN + i)) * DM + h * DD);
    #pragma unroll
    for (int q = 0; q < 4; ++q) {
      uint4 v0 = ap[q];
      ah[q * 4 + 0] = u2h(v0.x); ah[q * 4 + 1] = u2h(v0.y);
      ah[q * 4 + 2] = u2h(v0.z); ah[q * 4 + 3] = u2h(v0.w);
    }
    const float4* fp = (const float4*)(aff + h * DD);
    const float afs = 0.4f * RLOG2E;
    #pragma unroll
    for (int q = 0; q < 8; ++q) {
      float4 fv = fp[q];
      afh[q * 2 + 0] = pkrtz(fv.x * afs, fv.y * afs);
      afh[q * 2 + 1] = pkrtz(fv.z * afs, fv.w * afs);
    }
  }
  const float sai = sa[(b * NH + h) * NN + i];
  const unsigned int mw = bits[((b * 16) + jh * 2 + (wu >> 1)) * NN + i] >> ((wu & 1) * 16);
  float l = 0.f;
  h2 ph[8];   // packed p for this wave's 16 j

  // wave-uniform base of this wave's B rows
  const uint4* Bw = (const uint4*)(Pfc2h + ((size_t)(b * NN + jbase + wu * 16)) * DM + h * DD);

  __syncthreads();

  // ---- phase 1: branch-free score loop (2 j per iter for static pkrtz packing) ----
  #pragma unroll
  for (int jp = 0; jp < 8; ++jp) {
    float pv2[2];
    #pragma unroll
    for (int q = 0; q < 2; ++q) {
      const int jo = jp * 2 + q;
      const uint4* bp = Bw + (size_t)jo * (DM / 8);
      uint4 bq0 = bp[0], bq1 = bp[1], bq2 = bp[2], bq3 = bp[3];
      float t0 = 0.f, t1 = 0.f;
      #define SC2(k, dw, T)                                          \
        { h2 bh = u2h(dw);                                           \
          h2 u0 = u2h(h2u(ah[k] + bh) & 0x7FFF7FFFu);                \
          T = DOT2(afh[k], u0, T); }
      SC2(0,  bq0.x, t0) SC2(1,  bq0.y, t1)
      SC2(2,  bq0.z, t0) SC2(3,  bq0.w, t1)
      SC2(4,  bq1.x, t0) SC2(5,  bq1.y, t1)
      SC2(6,  bq1.z, t0) SC2(7,  bq1.w, t1)
      SC2(8,  bq2.x, t0) SC2(9,  bq2.y, t1)
      SC2(10, bq2.z, t0) SC2(11, bq2.w, t1)
      SC2(12, bq3.x, t0) SC2(13, bq3.y, t1)
      SC2(14, bq3.z, t0) SC2(15, bq3.w, t1)
      #undef SC2
      const float s = sai + sbt[wu * 16 + jo] + (t0 + t1);
      const float p = ((mw >> jo) & 1u) ? __builtin_amdgcn_exp2f(s) : 0.f;
      l += p;
      pv2[q] = p;
    }
    ph[jp] = pkrtz(pv2[0], pv2[1]);
  }

  slm[wu][lane] = l;
  // write P row chunks (16 j = 2 x 16B), XOR swizzle chunk ^ (row&7)
  {
    const int c0 = 2 * wu, c1 = 2 * wu + 1;
    uint4 q0 = make_uint4(h2u(ph[0]), h2u(ph[1]), h2u(ph[2]), h2u(ph[3]));
    uint4 q1 = make_uint4(h2u(ph[4]), h2u(ph[5]), h2u(ph[6]), h2u(ph[7]));
    Pt4[lane * 8 + (c0 ^ (lane & 7))] = q0;
    Pt4[lane * 8 + (c1 ^ (lane & 7))] = q1;
  }
  __syncthreads();

  // ---- phase 2: O = P·V via MFMA 16x16x32 f16; wave w -> row-tile w ----
  {
    const int lr = lane & 15, lk = lane >> 4;
    const int row = wu * 16 + lr;
    uint4 a4_0 = Pt4[row * 8 + ((lk) ^ (row & 7))];
    uint4 a4_1 = Pt4[row * 8 + ((4 + lk) ^ (row & 7))];
    #pragma unroll
    for (int ct = 0; ct < 2; ++ct) {
      const int d = ct * 16 + lr;
      uint4 b4_0 = VtT4[d * 8 + ((lk) ^ (d & 7))];
      uint4 b4_1 = VtT4[d * 8 + ((4 + lk) ^ (d & 7))];
      f32x4 acc = {0.f, 0.f, 0.f, 0.f};
      acc = __builtin_amdgcn_mfma_f32_16x16x32_f16(u4h8(a4_0), u4h8(b4_0), acc, 0, 0, 0);
      acc = __builtin_amdgcn_mfma_f32_16x16x32_f16(u4h8(a4_1), u4h8(b4_1), acc, 0, 0, 0);
      // D: col = lane&15, row = (lane>>4)*4 + v
      #pragma unroll
      for (int v = 0; v < 4; ++v) {
        const int grow = it * 64 + wu * 16 + lk * 4 + v;
        const size_t prow = (((size_t)(jh * 2 + b) * NH + h) * NN + grow);
        part_oh[prow * 32 + ct * 16 + lr] = (_Float16)acc[v];
      }
    }
    if (tid < 64) {
      const size_t prow = (((size_t)(jh * 2 + b) * NH + h) * NN + it * 64 + tid);
      part_l[prow] = (slm[0][tid] + slm[1][tid]) + (slm[2][tid] + slm[3][tid]);
    }
  }
}

// ---------------- kernel 4: combine(8 slots) + residual + layernorm + relu ----------------
// grid 128 blocks x 256 thr; block = 8 rows; 32 threads/row, 16 d's each.
__global__ void comb_ln_kernel(const unsigned int* __restrict__ part_o,
                               const float* __restrict__ part_l,
                               const _Float16* __restrict__ Pfch,
                               const float* __restrict__ g, const float* __restrict__ be,
                               float* __restrict__ out) {
  const int t = threadIdx.x;
  const int rg = blockIdx.x * 8 + (t >> 5);     // global row 0..1023
  const int b = rg >> 9, i = rg & 511;
  const int l32 = t & 31;
  const int d0 = l32 * 16;
  const int h0 = d0 >> 5;
  const int dh = d0 & 31;                        // 0 or 16
  float o[16];
  #pragma unroll
  for (int k = 0; k < 16; ++k) o[k] = 0.f;
  float L = 0.f;
  #pragma unroll
  for (int s = 0; s < 8; ++s) {
    const size_t prow = (((size_t)(s * 2 + b) * NH + h0) * NN + i);
    L += part_l[prow];
    const uint4* po = (const uint4*)(part_o + prow * 16 + (dh >> 1));
    uint4 q0 = po[0], q1 = po[1];
    #define ACC(k, dw) { h2 hh = u2h(dw); o[2*(k)] += (float)hh[0]; o[2*(k)+1] += (float)hh[1]; }
    ACC(0, q0.x) ACC(1, q0.y) ACC(2, q0.z) ACC(3, q0.w)
    ACC(4, q1.x) ACC(5, q1.y) ACC(6, q1.z) ACC(7, q1.w)
    #undef ACC
  }
  const float inv = 1.f / L;
  // residual x_aff_flat from f16 Pfch
  const uint4* pfh = (const uint4*)(Pfch + ((size_t)(b * NN + i)) * DM + d0);
  uint4 r0 = pfh[0], r1 = pfh[1];
  float pfv[16];
  #define UNP(k, dw) { h2 hh = u2h(dw); pfv[2*(k)] = (float)hh[0]; pfv[2*(k)+1] = (float)hh[1]; }
  UNP(0, r0.x) UNP(1, r0.y) UNP(2, r0.z) UNP(3, r0.w)
  UNP(4, r1.x) UNP(5, r1.y) UNP(6, r1.z) UNP(7, r1.w)
  #undef UNP
  float hv[16];
  float sS = 0.f, sQ = 0.f;
  #pragma unroll
  for (int k = 0; k < 16; ++k) {
    float hvv = pfv[k] + o[k] * inv;
    hv[k] = hvv;
    sS += hvv;
    sQ = fmaf(hvv, hvv, sQ);
  }
  #pragma unroll
  for (int off = 16; off > 0; off >>= 1) {
    sS += __shfl_xor(sS, off);
    sQ += __shfl_xor(sQ, off);
  }
  const float mu = sS * (1.f / 512.f);
  const float var = sQ * (1.f / 512.f) - mu * mu;
  const float rstd = rsqrtf(var + 1e-5f);
  float4* op = (float4*)(out + ((size_t)(b * NN + i)) * DM + d0);
  #pragma unroll
  for (int k = 0; k < 4; ++k) {
    float4 gv = ((const float4*)(g + d0))[k];
    float4 bv = ((const float4*)(be + d0))[k];
    float4 res;
    res.x = fmaxf((hv[4 * k + 0] - mu) * rstd * gv.x + bv.x, 0.f);
    res.y = fmaxf((hv[4 * k + 1] - mu) * rstd * gv.y + bv.y, 0.f);
    res.z = fmaxf((hv[4 * k + 2] - mu) * rstd * gv.z + bv.z, 0.f);
    res.w = fmaxf((hv[4 * k + 3] - mu) * rstd * gv.w + bv.w, 0.f);
    op[k] = res;
  }
}

extern "C" void kernel_launch(void* const* d_in, const int* in_sizes, int n_in,
                              void* d_out, int out_size, void* d_ws, size_t ws_size,
                              hipStream_t stream) {
  const float* x    = (const float*)d_in[0];
  const float* adj  = (const float*)d_in[1];
  const float* Wfc  = (const float*)d_in[2];
  const float* bfc  = (const float*)d_in[3];
  const float* Wfc2 = (const float*)d_in[4];
  const float* bfc2 = (const float*)d_in[5];
  const float* Wval = (const float*)d_in[6];
  const float* bval = (const float*)d_in[7];
  const float* aff  = (const float*)d_in[8];
  // d_in[9] = aff_bias: softmax-invariant, skipped
  const float* lng  = (const float*)d_in[10];
  const float* lnb  = (const float*)d_in[11];
  float* out = (float*)d_out;

  char* ws = (char*)d_ws;
  // phase-1 staging [0, 2.62MB) -- dead after proj; part_oh overlays it.
  unsigned short* xb  = (unsigned short*)(ws);
  unsigned short* wb0 = (unsigned short*)(ws + 1048576);
  unsigned short* wb1 = (unsigned short*)(ws + 1572864);
  unsigned short* wb2 = (unsigned short*)(ws + 2097152);
  _Float16* part_oh = (_Float16*)(ws);                  // 8.4 MB (overlays staging)
  float* part_l   = (float*)(ws + 8388608);             // 512 KB
  _Float16* Pfch  = (_Float16*)(ws + 8912896);          // 1 MB
  _Float16* Pfc2h = (_Float16*)(ws + 9961472);          // 1 MB
  _Float16* Pvalh = (_Float16*)(ws + 11010048);         // 1 MB
  float* sa       = (float*)(ws + 12058624);            // 64 KB
  float* sb       = (float*)(ws + 12124160);            // 64 KB
  unsigned int* bits = (unsigned int*)(ws + 12189696);  // 64 KB
  // footprint: 12,255,232 bytes

  prep_kernel<<<1344, 256, 0, stream>>>(x, Wfc, Wfc2, Wval, adj, xb, wb0, wb1, wb2, bits);
  proj_kernel<<<dim3(16, 8, 3), 256, 0, stream>>>(xb, wb0, wb1, wb2, bfc, bfc2, bval, aff,
                                                  Pfch, Pfc2h, Pvalh, sa, sb);
  attn_kernel<<<dim3(64, 16, 2), 256, 0, stream>>>(Pfch, Pfc2h, Pvalh, sa, sb, aff, bits,
                                                   part_l, part_oh);
  comb_ln_kernel<<<128, 256, 0, stream>>>((const unsigned int*)part_oh, part_l, Pfch,
                                          lng, lnb, out);
}